// Round 1
// baseline (126.000 us; speedup 1.0000x reference)
//
#include <hip/hip_runtime.h>

typedef __bf16 bf16x8 __attribute__((ext_vector_type(8)));
typedef float f32x4 __attribute__((ext_vector_type(4)));

__device__ __forceinline__ unsigned short f2bf(float f) {
  union { float f; unsigned u; } x; x.f = f;
  unsigned r = x.u + 0x7fffu + ((x.u >> 16) & 1u);
  return (unsigned short)(r >> 16);
}

__device__ __forceinline__ void gl_lds16(const void* g, void* l) {
  __builtin_amdgcn_global_load_lds(
      (const __attribute__((address_space(1))) void*)g,
      (__attribute__((address_space(3))) void*)l, 16, 0, 0);
}

// ---------------- fp32 -> bf16 convert (vectorized) ----------------
__global__ __launch_bounds__(256) void convert_bf16(const float* __restrict__ in,
                                                    unsigned short* __restrict__ out,
                                                    long n) {
  long i = ((long)blockIdx.x * 256 + threadIdx.x) * 8;
  long stride = (long)gridDim.x * 256 * 8;
  for (; i < n; i += stride) {
    float4 a = *(const float4*)&in[i];
    float4 b = *(const float4*)&in[i + 4];
    ushort4 o0, o1;
    o0.x = f2bf(a.x); o0.y = f2bf(a.y); o0.z = f2bf(a.z); o0.w = f2bf(a.w);
    o1.x = f2bf(b.x); o1.y = f2bf(b.y); o1.z = f2bf(b.z); o1.w = f2bf(b.w);
    *(ushort4*)&out[i] = o0;
    *(ushort4*)&out[i + 4] = o1;
  }
}

// ---------------- x_middle [b][c][n] fp32 -> vt [b][n][c] bf16 ----------------
__global__ __launch_bounds__(256) void transpose_v(const float* __restrict__ xm,
                                                   unsigned short* __restrict__ vt) {
  __shared__ float t[32][33];
  const int b = blockIdx.z;
  const int n0 = blockIdx.x * 32;
  const int c0 = blockIdx.y * 32;
  const int tid = threadIdx.x;
  const int r = tid >> 3;          // 0..31
  const int q4 = (tid & 7) * 4;    // 0,4,...,28

  float4 v = *(const float4*)&xm[((long)b * 256 + c0 + r) * 4096 + n0 + q4];
  t[r][q4 + 0] = v.x; t[r][q4 + 1] = v.y; t[r][q4 + 2] = v.z; t[r][q4 + 3] = v.w;
  __syncthreads();
  ushort4 o;
  o.x = f2bf(t[q4 + 0][r]);
  o.y = f2bf(t[q4 + 1][r]);
  o.z = f2bf(t[q4 + 2][r]);
  o.w = f2bf(t[q4 + 3][r]);
  *(ushort4*)&vt[((long)b * 4096 + n0 + r) * 256 + c0 + q4] = o;
}

// ---------------- NT GEMM, 64x64 tile, 4 waves x 32x32, BK=64 ----------------
// MODE 0: O fp32 = scale * A*B^T           (sim)
// MODE 1: O bf16 = A*B^T                   (A = W * P)
// MODE 2: O fp32 = A*B^T + R               (out, residual)
template <int MODE>
__global__ __launch_bounds__(256) void gemm64(
    const unsigned short* __restrict__ Ag, long aStride, int lda,
    const unsigned short* __restrict__ Bg, long bStride, int ldb,
    void* __restrict__ Og, long oStride, int ldo,
    const float* __restrict__ Rg, long rStride,
    int K, int tn, float scale) {
  __shared__ __align__(16) unsigned short As[64 * 64];
  __shared__ __align__(16) unsigned short Bs[64 * 64];

  const int b = blockIdx.y;
  const int tm_i = blockIdx.x / tn;
  const int tn_i = blockIdx.x % tn;
  const int tid = threadIdx.x;
  const int wave = tid >> 6;
  const int lane = tid & 63;

  const unsigned short* A = Ag + b * aStride + (long)(tm_i * 64) * lda;
  const unsigned short* B = Bg + b * bStride + (long)(tn_i * 64) * ldb;

  // staging geometry: issue i covers LDS rows [i*8, i*8+8), this wave does i=wave*2, wave*2+1
  const int srow = wave * 16 + (lane >> 3);            // row for issue wave*2 (second issue: +8)
  const int schunk = (lane & 7) ^ (lane >> 3);         // pre-swizzled source chunk (involution)

  f32x4 acc[2][2];
#pragma unroll
  for (int i = 0; i < 2; ++i)
#pragma unroll
    for (int j = 0; j < 2; ++j) acc[i][j] = (f32x4)0.f;

  const int wr = (wave >> 1) * 32;
  const int wc = (wave & 1) * 32;
  const int fr = lane & 15;
  const int fq = lane >> 4;

  for (int k0 = 0; k0 < K; k0 += 64) {
    {
      const unsigned short* ga0 = A + (long)srow * lda + k0 + schunk * 8;
      const unsigned short* ga1 = A + (long)(srow + 8) * lda + k0 + schunk * 8;
      const unsigned short* gb0 = B + (long)srow * ldb + k0 + schunk * 8;
      const unsigned short* gb1 = B + (long)(srow + 8) * ldb + k0 + schunk * 8;
      gl_lds16(ga0, &As[(wave * 2 + 0) * 512]);
      gl_lds16(ga1, &As[(wave * 2 + 1) * 512]);
      gl_lds16(gb0, &Bs[(wave * 2 + 0) * 512]);
      gl_lds16(gb1, &Bs[(wave * 2 + 1) * 512]);
    }
    __syncthreads();  // drains vmcnt: LDS tiles ready
#pragma unroll
    for (int kk = 0; kk < 2; ++kk) {
      bf16x8 af[2], bfr[2];
#pragma unroll
      for (int mi = 0; mi < 2; ++mi) {
        int row = wr + mi * 16 + fr;
        int chunk = (kk * 4 + fq) ^ (row & 7);
        af[mi] = *(const bf16x8*)&As[row * 64 + chunk * 8];
      }
#pragma unroll
      for (int ni = 0; ni < 2; ++ni) {
        int row = wc + ni * 16 + fr;
        int chunk = (kk * 4 + fq) ^ (row & 7);
        bfr[ni] = *(const bf16x8*)&Bs[row * 64 + chunk * 8];
      }
#pragma unroll
      for (int mi = 0; mi < 2; ++mi)
#pragma unroll
        for (int ni = 0; ni < 2; ++ni)
          acc[mi][ni] =
              __builtin_amdgcn_mfma_f32_16x16x32_bf16(af[mi], bfr[ni], acc[mi][ni], 0, 0, 0);
    }
    __syncthreads();  // all reads done before next stage overwrites
  }

  // epilogue: C/D layout col = lane&15, row = (lane>>4)*4 + j
#pragma unroll
  for (int mi = 0; mi < 2; ++mi)
#pragma unroll
    for (int ni = 0; ni < 2; ++ni)
#pragma unroll
      for (int j = 0; j < 4; ++j) {
        const int r = tm_i * 64 + wr + mi * 16 + fq * 4 + j;
        const int c = tn_i * 64 + wc + ni * 16 + fr;
        if constexpr (MODE == 0) {
          float* O = (float*)Og + b * oStride;
          O[(long)r * ldo + c] = scale * acc[mi][ni][j];
        } else if constexpr (MODE == 1) {
          unsigned short* O = (unsigned short*)Og + b * oStride;
          O[(long)r * ldo + c] = f2bf(acc[mi][ni][j]);
        } else {
          float* O = (float*)Og + b * oStride;
          const float* R = Rg + b * rStride;
          const long idx = (long)r * ldo + c;
          O[idx] = acc[mi][ni][j] + R[idx];
        }
      }
}

// ---------------- row softmax over d, output transposed Ps[b][d][c] bf16 ----------------
__global__ __launch_bounds__(256) void softmax_t(const float* __restrict__ sim,
                                                 unsigned short* __restrict__ Ps) {
  const int wave = threadIdx.x >> 6;
  const int lane = threadIdx.x & 63;
  const int gid = blockIdx.x * 4 + wave;  // row index b*256+c
  const int b = gid >> 8;
  const int c = gid & 255;

  const float* row = sim + (long)gid * 256;
  float4 v = *(const float4*)&row[lane * 4];
  float m = fmaxf(fmaxf(v.x, v.y), fmaxf(v.z, v.w));
#pragma unroll
  for (int off = 32; off; off >>= 1) m = fmaxf(m, __shfl_xor(m, off));
  float e0 = expf(v.x - m), e1 = expf(v.y - m), e2 = expf(v.z - m), e3 = expf(v.w - m);
  float s = e0 + e1 + e2 + e3;
#pragma unroll
  for (int off = 32; off; off >>= 1) s += __shfl_xor(s, off);
  const float inv = 1.0f / s;
  unsigned short* colp = Ps + (long)b * 65536 + c;
  colp[(lane * 4 + 0) * 256] = f2bf(e0 * inv);
  colp[(lane * 4 + 1) * 256] = f2bf(e1 * inv);
  colp[(lane * 4 + 2) * 256] = f2bf(e2 * inv);
  colp[(lane * 4 + 3) * 256] = f2bf(e3 * inv);
}

extern "C" void kernel_launch(void* const* d_in, const int* in_sizes, int n_in,
                              void* d_out, int out_size, void* d_ws, size_t ws_size,
                              hipStream_t stream) {
  const float* x = (const float*)d_in[0];
  const float* xm = (const float*)d_in[1];
  const float* w = (const float*)d_in[2];
  float* out = (float*)d_out;

  const long B = 16, C = 256, N = 4096;

  unsigned short* xb = (unsigned short*)d_ws;        // [B][C][N] bf16
  unsigned short* vt = xb + B * C * N;               // [B][N][C] bf16
  float* sim = (float*)(vt + B * N * C);             // [B][C][C] fp32
  unsigned short* Ps = (unsigned short*)(sim + B * C * C);  // [B][d][c] bf16
  unsigned short* Ab = Ps + B * C * C;               // [B][o][d] bf16
  unsigned short* wb = Ab + B * C * C;               // [o][c] bf16

  // 1) x -> bf16
  convert_bf16<<<dim3(8192), dim3(256), 0, stream>>>(x, xb, B * C * N);
  // 2) w_conv -> bf16
  convert_bf16<<<dim3(32), dim3(256), 0, stream>>>(w, wb, C * C);
  // 3) x_middle -> vt (transposed bf16)
  transpose_v<<<dim3(128, 8, 16), dim3(256), 0, stream>>>(xm, vt);
  // 4) sim = scale * q q^T   (M=N=256, K=4096)
  gemm64<0><<<dim3(16, 16), dim3(256), 0, stream>>>(
      xb, C * N, (int)N, xb, C * N, (int)N, sim, C * C, (int)C,
      (const float*)nullptr, 0L, (int)N, 4, 0.0625f);
  // 5) P = softmax(sim), stored transposed
  softmax_t<<<dim3(1024), dim3(256), 0, stream>>>(sim, Ps);
  // 6) Ab = W * P           (M=256, N=256, K=256)
  gemm64<1><<<dim3(16, 16), dim3(256), 0, stream>>>(
      wb, 0L, (int)C, Ps, C * C, (int)C, Ab, C * C, (int)C,
      (const float*)nullptr, 0L, (int)C, 4, 1.0f);
  // 7) out = Ab * v + x_middle   (M=256, N=4096, K=256)
  gemm64<2><<<dim3(256, 16), dim3(256), 0, stream>>>(
      Ab, C * C, (int)C, vt, N * C, (int)C, out, C * N, (int)N,
      xm, C * N, (int)C, 64, 1.0f);
}

// Round 2
// 100.708 us; speedup vs baseline: 1.2511x; 1.2511x over previous
//
#include <hip/hip_runtime.h>

typedef __bf16 bf16x8 __attribute__((ext_vector_type(8)));
typedef float f32x4 __attribute__((ext_vector_type(4)));

__device__ __forceinline__ unsigned short f2bf(float f) {
  union { float f; unsigned u; } x; x.f = f;
  unsigned r = x.u + 0x7fffu + ((x.u >> 16) & 1u);
  return (unsigned short)(r >> 16);
}

__device__ __forceinline__ void gl_lds16(const void* g, void* l) {
  __builtin_amdgcn_global_load_lds(
      (const __attribute__((address_space(1))) void*)g,
      (__attribute__((address_space(3))) void*)l, 16, 0, 0);
}

// ---------------- fp32 -> bf16 convert (vectorized) ----------------
__global__ __launch_bounds__(256) void convert_bf16(const float* __restrict__ in,
                                                    unsigned short* __restrict__ out,
                                                    long n) {
  long i = ((long)blockIdx.x * 256 + threadIdx.x) * 8;
  long stride = (long)gridDim.x * 256 * 8;
  for (; i < n; i += stride) {
    float4 a = *(const float4*)&in[i];
    float4 b = *(const float4*)&in[i + 4];
    ushort4 o0, o1;
    o0.x = f2bf(a.x); o0.y = f2bf(a.y); o0.z = f2bf(a.z); o0.w = f2bf(a.w);
    o1.x = f2bf(b.x); o1.y = f2bf(b.y); o1.z = f2bf(b.z); o1.w = f2bf(b.w);
    *(ushort4*)&out[i] = o0;
    *(ushort4*)&out[i + 4] = o1;
  }
}

// ---------------- x_middle [b][c][n] fp32 -> vt [b][n][c] bf16 ----------------
__global__ __launch_bounds__(256) void transpose_v(const float* __restrict__ xm,
                                                   unsigned short* __restrict__ vt) {
  __shared__ float t[32][33];
  const int b = blockIdx.z;
  const int n0 = blockIdx.x * 32;
  const int c0 = blockIdx.y * 32;
  const int tid = threadIdx.x;
  const int r = tid >> 3;          // 0..31
  const int q4 = (tid & 7) * 4;    // 0,4,...,28

  float4 v = *(const float4*)&xm[((long)b * 256 + c0 + r) * 4096 + n0 + q4];
  t[r][q4 + 0] = v.x; t[r][q4 + 1] = v.y; t[r][q4 + 2] = v.z; t[r][q4 + 3] = v.w;
  __syncthreads();
  ushort4 o;
  o.x = f2bf(t[q4 + 0][r]);
  o.y = f2bf(t[q4 + 1][r]);
  o.z = f2bf(t[q4 + 2][r]);
  o.w = f2bf(t[q4 + 3][r]);
  *(ushort4*)&vt[((long)b * 4096 + n0 + r) * 256 + c0 + q4] = o;
}

// ---------------- sim split-K GEMM: simP[q][b][256][256] += scale*(q_panel q_panel^T) ----
// 2048 WGs; XCD-clustering swizzle: XCD = j%8 owns 16 whole (batch,chunk) panels.
__global__ __launch_bounds__(256) void sim_split(const unsigned short* __restrict__ xb,
                                                 float* __restrict__ simP) {
  __shared__ __align__(16) unsigned short As[64 * 64];
  __shared__ __align__(16) unsigned short Bs[64 * 64];

  const int j = blockIdx.x;          // 0..2047
  const int xcd = j & 7;
  const int slot = j >> 3;           // 0..255
  const int p = xcd * 16 + (slot >> 4);  // panel 0..127
  const int t = slot & 15;           // tile within panel
  const int b = p & 15;              // batch
  const int q = p >> 4;              // k-chunk 0..7
  const int tm_i = t >> 2;
  const int tn_i = t & 3;

  const int tid = threadIdx.x;
  const int wave = tid >> 6;
  const int lane = tid & 63;

  const unsigned short* A = xb + (long)b * 256 * 4096 + (long)(tm_i * 64) * 4096;
  const unsigned short* B = xb + (long)b * 256 * 4096 + (long)(tn_i * 64) * 4096;

  const int srow = wave * 16 + (lane >> 3);
  const int schunk = (lane & 7) ^ (lane >> 3);

  f32x4 acc[2][2];
#pragma unroll
  for (int i = 0; i < 2; ++i)
#pragma unroll
    for (int jj = 0; jj < 2; ++jj) acc[i][jj] = (f32x4)0.f;

  const int wr = (wave >> 1) * 32;
  const int wc = (wave & 1) * 32;
  const int fr = lane & 15;
  const int fq = lane >> 4;

  const int k0base = q * 512;
  for (int k0 = k0base; k0 < k0base + 512; k0 += 64) {
    gl_lds16(A + (long)srow * 4096 + k0 + schunk * 8, &As[(wave * 2 + 0) * 512]);
    gl_lds16(A + (long)(srow + 8) * 4096 + k0 + schunk * 8, &As[(wave * 2 + 1) * 512]);
    gl_lds16(B + (long)srow * 4096 + k0 + schunk * 8, &Bs[(wave * 2 + 0) * 512]);
    gl_lds16(B + (long)(srow + 8) * 4096 + k0 + schunk * 8, &Bs[(wave * 2 + 1) * 512]);
    __syncthreads();
#pragma unroll
    for (int kk = 0; kk < 2; ++kk) {
      bf16x8 af[2], bfr[2];
#pragma unroll
      for (int mi = 0; mi < 2; ++mi) {
        int row = wr + mi * 16 + fr;
        int chunk = (kk * 4 + fq) ^ (row & 7);
        af[mi] = *(const bf16x8*)&As[row * 64 + chunk * 8];
      }
#pragma unroll
      for (int ni = 0; ni < 2; ++ni) {
        int row = wc + ni * 16 + fr;
        int chunk = (kk * 4 + fq) ^ (row & 7);
        bfr[ni] = *(const bf16x8*)&Bs[row * 64 + chunk * 8];
      }
#pragma unroll
      for (int mi = 0; mi < 2; ++mi)
#pragma unroll
        for (int ni = 0; ni < 2; ++ni)
          acc[mi][ni] =
              __builtin_amdgcn_mfma_f32_16x16x32_bf16(af[mi], bfr[ni], acc[mi][ni], 0, 0, 0);
    }
    __syncthreads();
  }

  float* O = simP + (long)(q * 16 + b) * 65536;
#pragma unroll
  for (int mi = 0; mi < 2; ++mi)
#pragma unroll
    for (int ni = 0; ni < 2; ++ni)
#pragma unroll
      for (int jj = 0; jj < 4; ++jj) {
        const int r = tm_i * 64 + wr + mi * 16 + fq * 4 + jj;
        const int c = tn_i * 64 + wc + ni * 16 + fr;
        O[(long)r * 256 + c] = 0.0625f * acc[mi][ni][jj];
      }
}

// ---------------- NT GEMM, 64x64 tile, 4 waves x 32x32, BK=64 ----------------
// MODE 1: O bf16 = A*B^T                   (A = W * P)
// MODE 2: O fp32 = A*B^T + R               (out, residual)
template <int MODE>
__global__ __launch_bounds__(256) void gemm64(
    const unsigned short* __restrict__ Ag, long aStride, int lda,
    const unsigned short* __restrict__ Bg, long bStride, int ldb,
    void* __restrict__ Og, long oStride, int ldo,
    const float* __restrict__ Rg, long rStride,
    int K, int tn) {
  __shared__ __align__(16) unsigned short As[64 * 64];
  __shared__ __align__(16) unsigned short Bs[64 * 64];

  const int b = blockIdx.y;
  const int tm_i = blockIdx.x / tn;
  const int tn_i = blockIdx.x % tn;
  const int tid = threadIdx.x;
  const int wave = tid >> 6;
  const int lane = tid & 63;

  const unsigned short* A = Ag + b * aStride + (long)(tm_i * 64) * lda;
  const unsigned short* B = Bg + b * bStride + (long)(tn_i * 64) * ldb;

  const int srow = wave * 16 + (lane >> 3);
  const int schunk = (lane & 7) ^ (lane >> 3);

  f32x4 acc[2][2];
#pragma unroll
  for (int i = 0; i < 2; ++i)
#pragma unroll
    for (int j = 0; j < 2; ++j) acc[i][j] = (f32x4)0.f;

  const int wr = (wave >> 1) * 32;
  const int wc = (wave & 1) * 32;
  const int fr = lane & 15;
  const int fq = lane >> 4;

  for (int k0 = 0; k0 < K; k0 += 64) {
    gl_lds16(A + (long)srow * lda + k0 + schunk * 8, &As[(wave * 2 + 0) * 512]);
    gl_lds16(A + (long)(srow + 8) * lda + k0 + schunk * 8, &As[(wave * 2 + 1) * 512]);
    gl_lds16(B + (long)srow * ldb + k0 + schunk * 8, &Bs[(wave * 2 + 0) * 512]);
    gl_lds16(B + (long)(srow + 8) * ldb + k0 + schunk * 8, &Bs[(wave * 2 + 1) * 512]);
    __syncthreads();
#pragma unroll
    for (int kk = 0; kk < 2; ++kk) {
      bf16x8 af[2], bfr[2];
#pragma unroll
      for (int mi = 0; mi < 2; ++mi) {
        int row = wr + mi * 16 + fr;
        int chunk = (kk * 4 + fq) ^ (row & 7);
        af[mi] = *(const bf16x8*)&As[row * 64 + chunk * 8];
      }
#pragma unroll
      for (int ni = 0; ni < 2; ++ni) {
        int row = wc + ni * 16 + fr;
        int chunk = (kk * 4 + fq) ^ (row & 7);
        bfr[ni] = *(const bf16x8*)&Bs[row * 64 + chunk * 8];
      }
#pragma unroll
      for (int mi = 0; mi < 2; ++mi)
#pragma unroll
        for (int ni = 0; ni < 2; ++ni)
          acc[mi][ni] =
              __builtin_amdgcn_mfma_f32_16x16x32_bf16(af[mi], bfr[ni], acc[mi][ni], 0, 0, 0);
    }
    __syncthreads();
  }

#pragma unroll
  for (int mi = 0; mi < 2; ++mi)
#pragma unroll
    for (int ni = 0; ni < 2; ++ni)
#pragma unroll
      for (int j = 0; j < 4; ++j) {
        const int r = tm_i * 64 + wr + mi * 16 + fq * 4 + j;
        const int c = tn_i * 64 + wc + ni * 16 + fr;
        if constexpr (MODE == 1) {
          unsigned short* O = (unsigned short*)Og + b * oStride;
          O[(long)r * ldo + c] = f2bf(acc[mi][ni][j]);
        } else {
          float* O = (float*)Og + b * oStride;
          const float* R = Rg + b * rStride;
          const long idx = (long)r * ldo + c;
          O[idx] = acc[mi][ni][j] + R[idx];
        }
      }
}

// -------- softmax over d with 8-way split-K reduction; output transposed Ps[b][d][c] bf16 ----
__global__ __launch_bounds__(256) void softmax8(const float* __restrict__ simP,
                                                unsigned short* __restrict__ Ps) {
  const int wave = threadIdx.x >> 6;
  const int lane = threadIdx.x & 63;
  const int gid = blockIdx.x * 4 + wave;  // row index b*256+c
  const int b = gid >> 8;
  const int c = gid & 255;

  float4 v = make_float4(0.f, 0.f, 0.f, 0.f);
#pragma unroll
  for (int q = 0; q < 8; ++q) {
    float4 pv = *(const float4*)&simP[(long)(q * 16 + b) * 65536 + (long)c * 256 + lane * 4];
    v.x += pv.x; v.y += pv.y; v.z += pv.z; v.w += pv.w;
  }
  float m = fmaxf(fmaxf(v.x, v.y), fmaxf(v.z, v.w));
#pragma unroll
  for (int off = 32; off; off >>= 1) m = fmaxf(m, __shfl_xor(m, off));
  float e0 = expf(v.x - m), e1 = expf(v.y - m), e2 = expf(v.z - m), e3 = expf(v.w - m);
  float s = e0 + e1 + e2 + e3;
#pragma unroll
  for (int off = 32; off; off >>= 1) s += __shfl_xor(s, off);
  const float inv = 1.0f / s;
  unsigned short* colp = Ps + (long)b * 65536 + c;
  colp[(lane * 4 + 0) * 256] = f2bf(e0 * inv);
  colp[(lane * 4 + 1) * 256] = f2bf(e1 * inv);
  colp[(lane * 4 + 2) * 256] = f2bf(e2 * inv);
  colp[(lane * 4 + 3) * 256] = f2bf(e3 * inv);
}

extern "C" void kernel_launch(void* const* d_in, const int* in_sizes, int n_in,
                              void* d_out, int out_size, void* d_ws, size_t ws_size,
                              hipStream_t stream) {
  const float* x = (const float*)d_in[0];
  const float* xm = (const float*)d_in[1];
  const float* w = (const float*)d_in[2];
  float* out = (float*)d_out;

  const long B = 16, C = 256, N = 4096;

  // Workspace layout (vt aliases xb: xb dead after sim_split, stream-ordered):
  unsigned short* xb = (unsigned short*)d_ws;               // [B][C][N] bf16 (33.55 MB)
  unsigned short* vt = xb;                                  // [B][N][C] bf16 (same region)
  float* simP = (float*)(xb + B * C * N);                   // [8][B][C][C] fp32 (33.55 MB)
  unsigned short* Ps = (unsigned short*)(simP + 8 * B * C * C);  // [B][d][c] bf16 (2 MB)
  unsigned short* Ab = Ps + B * C * C;                      // [B][o][d] bf16 (2 MB)
  unsigned short* wb = Ab + B * C * C;                      // [o][c] bf16 (128 KB)

  // 1) x -> bf16
  convert_bf16<<<dim3(8192), dim3(256), 0, stream>>>(x, xb, B * C * N);
  // 2) w_conv -> bf16
  convert_bf16<<<dim3(32), dim3(256), 0, stream>>>(w, wb, C * C);
  // 3) simP = split-K partials of scale * q q^T
  sim_split<<<dim3(2048), dim3(256), 0, stream>>>(xb, simP);
  // 4) P = softmax(sum_q simP), stored transposed  (xb now dead)
  softmax8<<<dim3(1024), dim3(256), 0, stream>>>(simP, Ps);
  // 5) x_middle -> vt (transposed bf16; overwrites xb region)
  transpose_v<<<dim3(128, 8, 16), dim3(256), 0, stream>>>(xm, vt);
  // 6) Ab = W * P           (M=256, N=256, K=256)
  gemm64<1><<<dim3(16, 16), dim3(256), 0, stream>>>(
      wb, 0L, (int)C, Ps, C * C, (int)C, Ab, C * C, (int)C,
      (const float*)nullptr, 0L, 256, 4);
  // 7) out = Ab * v + x_middle   (M=256, N=4096, K=256)
  gemm64<2><<<dim3(256, 16), dim3(256), 0, stream>>>(
      Ab, C * C, (int)C, vt, N * C, (int)C, out, C * N, (int)N,
      xm, C * N, 256, 64);
}

// Round 3
// 89.320 us; speedup vs baseline: 1.4107x; 1.1275x over previous
//
#include <hip/hip_runtime.h>

typedef __bf16 bf16x8 __attribute__((ext_vector_type(8)));
typedef float f32x4 __attribute__((ext_vector_type(4)));

__device__ __forceinline__ unsigned short f2bf(float f) {
  union { float f; unsigned u; } x; x.f = f;
  unsigned r = x.u + 0x7fffu + ((x.u >> 16) & 1u);
  return (unsigned short)(r >> 16);
}

__device__ __forceinline__ void gl_lds16(const void* g, void* l) {
  __builtin_amdgcn_global_load_lds(
      (const __attribute__((address_space(1))) void*)g,
      (__attribute__((address_space(3))) void*)l, 16, 0, 0);
}

// convert 16 consecutive floats at p into two bf16x8 halves
__device__ __forceinline__ void cvt16(const float* p, bf16x8& h0, bf16x8& h1) {
  float4 a0 = *(const float4*)(p);
  float4 a1 = *(const float4*)(p + 4);
  float4 a2 = *(const float4*)(p + 8);
  float4 a3 = *(const float4*)(p + 12);
  h0[0] = (__bf16)a0.x; h0[1] = (__bf16)a0.y; h0[2] = (__bf16)a0.z; h0[3] = (__bf16)a0.w;
  h0[4] = (__bf16)a1.x; h0[5] = (__bf16)a1.y; h0[6] = (__bf16)a1.z; h0[7] = (__bf16)a1.w;
  h1[0] = (__bf16)a2.x; h1[1] = (__bf16)a2.y; h1[2] = (__bf16)a2.z; h1[3] = (__bf16)a2.w;
  h1[4] = (__bf16)a3.x; h1[5] = (__bf16)a3.y; h1[6] = (__bf16)a3.z; h1[7] = (__bf16)a3.w;
}

// ---------------- fp32 -> bf16 convert (w_conv only) ----------------
__global__ __launch_bounds__(256) void convert_bf16(const float* __restrict__ in,
                                                    unsigned short* __restrict__ out,
                                                    long n) {
  long i = ((long)blockIdx.x * 256 + threadIdx.x) * 8;
  if (i >= n) return;
  bf16x8 h0, h1;
  cvt16(&in[i & ~15L], h0, h1);  // n multiple of 16 here; pick correct half
  bf16x8 h = (i & 8) ? h1 : h0;
  *(bf16x8*)&out[i] = h;
}

// ---- sim split-K GEMM with fused fp32->bf16 convert ----
// simP[q][b][256][256] = 0.0625 * (x_panel x_panel^T), K-chunk q of 4 (K=1024 each)
// grid 1024, XCD-clustered: each XCD owns 8 (b,q) panels (2 batches).
__global__ __launch_bounds__(256) void sim_split(const float* __restrict__ x,
                                                 float* __restrict__ simP) {
  __shared__ __align__(16) unsigned short As[4096];
  __shared__ __align__(16) unsigned short Bs[4096];

  const int j = blockIdx.x;            // 0..1023
  const int xcd = j & 7, s = j >> 3;   // s 0..127
  const int p = xcd * 8 + (s >> 4);    // panel 0..63
  const int t = s & 15;                // tile in panel
  const int b = p >> 2, q = p & 3;
  const int tm = t >> 2, tn = t & 3;

  const int tid = threadIdx.x;
  const int wave = tid >> 6, lane = tid & 63;
  const float* xA = x + (long)b * 1048576 + (long)(tm * 64) * 4096;
  const float* xB = x + (long)b * 1048576 + (long)(tn * 64) * 4096;
  const bool diag = (tm == tn);

  const int r = tid >> 2, kq = tid & 3;  // staging: row 0..63, k-quarter
  const int wr = (wave >> 1) * 32, wc = (wave & 1) * 32;
  const int fr = lane & 15, fq = lane >> 4;

  f32x4 acc[2][2];
#pragma unroll
  for (int i = 0; i < 2; ++i)
#pragma unroll
    for (int jj = 0; jj < 2; ++jj) acc[i][jj] = (f32x4)0.f;

  const int c0 = ((kq * 2) ^ (r & 7)) * 8;
  const int c1 = ((kq * 2 + 1) ^ (r & 7)) * 8;

  for (int k0 = q * 1024; k0 < q * 1024 + 1024; k0 += 64) {
    {
      bf16x8 h0, h1;
      cvt16(xA + (long)r * 4096 + k0 + kq * 16, h0, h1);
      *(bf16x8*)&As[r * 64 + c0] = h0;
      *(bf16x8*)&As[r * 64 + c1] = h1;
      if (!diag) {
        cvt16(xB + (long)r * 4096 + k0 + kq * 16, h0, h1);
        *(bf16x8*)&Bs[r * 64 + c0] = h0;
        *(bf16x8*)&Bs[r * 64 + c1] = h1;
      }
    }
    __syncthreads();
    const unsigned short* Bp = diag ? As : Bs;
#pragma unroll
    for (int kk = 0; kk < 2; ++kk) {
      bf16x8 af[2], bfr[2];
#pragma unroll
      for (int mi = 0; mi < 2; ++mi) {
        int row = wr + mi * 16 + fr;
        int chunk = (kk * 4 + fq) ^ (row & 7);
        af[mi] = *(const bf16x8*)&As[row * 64 + chunk * 8];
      }
#pragma unroll
      for (int ni = 0; ni < 2; ++ni) {
        int row = wc + ni * 16 + fr;
        int chunk = (kk * 4 + fq) ^ (row & 7);
        bfr[ni] = *(const bf16x8*)&Bp[row * 64 + chunk * 8];
      }
#pragma unroll
      for (int mi = 0; mi < 2; ++mi)
#pragma unroll
        for (int ni = 0; ni < 2; ++ni)
          acc[mi][ni] =
              __builtin_amdgcn_mfma_f32_16x16x32_bf16(af[mi], bfr[ni], acc[mi][ni], 0, 0, 0);
    }
    __syncthreads();
  }

  float* O = simP + (long)(q * 16 + b) * 65536;
#pragma unroll
  for (int mi = 0; mi < 2; ++mi)
#pragma unroll
    for (int ni = 0; ni < 2; ++ni)
#pragma unroll
      for (int jj = 0; jj < 4; ++jj) {
        const int rr = tm * 64 + wr + mi * 16 + fq * 4 + jj;
        const int cc = tn * 64 + wc + ni * 16 + fr;
        O[(long)rr * 256 + cc] = 0.0625f * acc[mi][ni][jj];
      }
}

// -------- softmax over d, 4-way split-K reduce; output transposed Ps[b][d][c] bf16 ----
__global__ __launch_bounds__(256) void softmax4(const float* __restrict__ simP,
                                                unsigned short* __restrict__ Ps) {
  const int wave = threadIdx.x >> 6;
  const int lane = threadIdx.x & 63;
  const int gid = blockIdx.x * 4 + wave;  // row index b*256+c
  const int b = gid >> 8;
  const int c = gid & 255;

  float4 v = make_float4(0.f, 0.f, 0.f, 0.f);
#pragma unroll
  for (int q = 0; q < 4; ++q) {
    float4 pv = *(const float4*)&simP[(long)(q * 16 + b) * 65536 + (long)c * 256 + lane * 4];
    v.x += pv.x; v.y += pv.y; v.z += pv.z; v.w += pv.w;
  }
  float m = fmaxf(fmaxf(v.x, v.y), fmaxf(v.z, v.w));
#pragma unroll
  for (int off = 32; off; off >>= 1) m = fmaxf(m, __shfl_xor(m, off));
  float e0 = expf(v.x - m), e1 = expf(v.y - m), e2 = expf(v.z - m), e3 = expf(v.w - m);
  float s = e0 + e1 + e2 + e3;
#pragma unroll
  for (int off = 32; off; off >>= 1) s += __shfl_xor(s, off);
  const float inv = 1.0f / s;
  unsigned short* colp = Ps + (long)b * 65536 + c;
  colp[(lane * 4 + 0) * 256] = f2bf(e0 * inv);
  colp[(lane * 4 + 1) * 256] = f2bf(e1 * inv);
  colp[(lane * 4 + 2) * 256] = f2bf(e2 * inv);
  colp[(lane * 4 + 3) * 256] = f2bf(e3 * inv);
}

// -------- Ab = W * P + I  (NT, M=N=K=256, bf16 out) --------
__global__ __launch_bounds__(256) void gemm_wp(const unsigned short* __restrict__ wb,
                                               const unsigned short* __restrict__ Ps,
                                               unsigned short* __restrict__ Ab) {
  __shared__ __align__(16) unsigned short As[4096];
  __shared__ __align__(16) unsigned short Bs[4096];
  const int b = blockIdx.y;
  const int tm = blockIdx.x >> 2, tn = blockIdx.x & 3;
  const int tid = threadIdx.x;
  const int wave = tid >> 6, lane = tid & 63;

  const unsigned short* A = wb + (long)(tm * 64) * 256;
  const unsigned short* B = Ps + (long)b * 65536 + (long)(tn * 64) * 256;

  const int srow = wave * 16 + (lane >> 3);
  const int schunk = (lane & 7) ^ (lane >> 3);
  const int wr = (wave >> 1) * 32, wc = (wave & 1) * 32;
  const int fr = lane & 15, fq = lane >> 4;

  f32x4 acc[2][2];
#pragma unroll
  for (int i = 0; i < 2; ++i)
#pragma unroll
    for (int jj = 0; jj < 2; ++jj) acc[i][jj] = (f32x4)0.f;

  for (int k0 = 0; k0 < 256; k0 += 64) {
    gl_lds16(A + (long)srow * 256 + k0 + schunk * 8, &As[(wave * 2 + 0) * 512]);
    gl_lds16(A + (long)(srow + 8) * 256 + k0 + schunk * 8, &As[(wave * 2 + 1) * 512]);
    gl_lds16(B + (long)srow * 256 + k0 + schunk * 8, &Bs[(wave * 2 + 0) * 512]);
    gl_lds16(B + (long)(srow + 8) * 256 + k0 + schunk * 8, &Bs[(wave * 2 + 1) * 512]);
    __syncthreads();
#pragma unroll
    for (int kk = 0; kk < 2; ++kk) {
      bf16x8 af[2], bfr[2];
#pragma unroll
      for (int mi = 0; mi < 2; ++mi) {
        int row = wr + mi * 16 + fr;
        int chunk = (kk * 4 + fq) ^ (row & 7);
        af[mi] = *(const bf16x8*)&As[row * 64 + chunk * 8];
      }
#pragma unroll
      for (int ni = 0; ni < 2; ++ni) {
        int row = wc + ni * 16 + fr;
        int chunk = (kk * 4 + fq) ^ (row & 7);
        bfr[ni] = *(const bf16x8*)&Bs[row * 64 + chunk * 8];
      }
#pragma unroll
      for (int mi = 0; mi < 2; ++mi)
#pragma unroll
        for (int ni = 0; ni < 2; ++ni)
          acc[mi][ni] =
              __builtin_amdgcn_mfma_f32_16x16x32_bf16(af[mi], bfr[ni], acc[mi][ni], 0, 0, 0);
    }
    __syncthreads();
  }

  unsigned short* O = Ab + (long)b * 65536;
#pragma unroll
  for (int mi = 0; mi < 2; ++mi)
#pragma unroll
    for (int ni = 0; ni < 2; ++ni)
#pragma unroll
      for (int jj = 0; jj < 4; ++jj) {
        const int rr = tm * 64 + wr + mi * 16 + fq * 4 + jj;
        const int cc = tn * 64 + wc + ni * 16 + fr;
        float val = acc[mi][ni][jj] + (rr == cc ? 1.0f : 0.0f);  // residual: +I
        O[(long)rr * 256 + cc] = f2bf(val);
      }
}

// -------- out = (W*P + I) * v, v = xm (fp32 [d][n], transposed+converted in-kernel) ----
// tile 64o x 64n, K=256 (BK=64). grid 4096 flat, XCD-clustered (2 batches/XCD,
// tm-quads of the same (b,tn) adjacent so the B panel is an L2 hit).
__global__ __launch_bounds__(256) void gemm_out(const unsigned short* __restrict__ Ab,
                                                const float* __restrict__ xm,
                                                float* __restrict__ out) {
  __shared__ __align__(16) unsigned short As[4096];   // [o 64][d 64] swizzled
  __shared__ __align__(16) float Bstage[64 * 68];     // [d 64][n 64 +4 pad]
  __shared__ __align__(16) unsigned short Bs[4096];   // [n 64][d 64] swizzled

  const int j = blockIdx.x;            // 0..4095
  const int xcd = j & 7, s = j >> 3;   // s 0..511
  const int tm = s & 3;
  const int g = xcd * 128 + (s >> 2);  // 0..1023
  const int b = g >> 6, tn = g & 63;

  const int tid = threadIdx.x;
  const int wave = tid >> 6, lane = tid & 63;
  const int n0 = tn * 64;

  const unsigned short* A = Ab + (long)b * 65536 + (long)(tm * 64) * 256;
  const float* Xb = xm + (long)b * 1048576;
  float* Ob = out + (long)b * 1048576;

  const int srow = wave * 16 + (lane >> 3);
  const int schunk = (lane & 7) ^ (lane >> 3);
  const int wr = (wave >> 1) * 32, wc = (wave & 1) * 32;
  const int fr = lane & 15, fq = lane >> 4;

  // B fp32 staging coords: row (d) 0..63, 16-col quarter
  const int br = tid >> 2, bq = tid & 3;
  // transpose coords: n row = lane, d-quarter = wave
  const int nn = lane, dq = wave;
  const int tc0 = ((dq * 2) ^ (nn & 7)) * 8;
  const int tc1 = ((dq * 2 + 1) ^ (nn & 7)) * 8;

  f32x4 acc[2][2];
#pragma unroll
  for (int i = 0; i < 2; ++i)
#pragma unroll
    for (int jj = 0; jj < 2; ++jj) acc[i][jj] = (f32x4)0.f;

  for (int k0 = 0; k0 < 256; k0 += 64) {
    // A tile: async DMA to linear LDS (pre-swizzled source)
    gl_lds16(A + (long)srow * 256 + k0 + schunk * 8, &As[(wave * 2 + 0) * 512]);
    gl_lds16(A + (long)(srow + 8) * 256 + k0 + schunk * 8, &As[(wave * 2 + 1) * 512]);
    // B tile fp32 stage: coalesced rows of xm[d][n]
    {
      const float* src = Xb + (long)(k0 + br) * 4096 + n0 + bq * 16;
#pragma unroll
      for (int i = 0; i < 4; ++i) {
        float4 vv = *(const float4*)(src + i * 4);
        *(float4*)&Bstage[br * 68 + bq * 16 + i * 4] = vv;
      }
    }
    __syncthreads();  // Bstage ready; vmcnt drained -> As ready
    // transpose + convert: column reads (pad 68 -> conflict-free), swizzled writes
    {
      bf16x8 h0, h1;
#pragma unroll
      for (int e = 0; e < 8; ++e) h0[e] = (__bf16)Bstage[(dq * 16 + e) * 68 + nn];
#pragma unroll
      for (int e = 0; e < 8; ++e) h1[e] = (__bf16)Bstage[(dq * 16 + 8 + e) * 68 + nn];
      *(bf16x8*)&Bs[nn * 64 + tc0] = h0;
      *(bf16x8*)&Bs[nn * 64 + tc1] = h1;
    }
    __syncthreads();
#pragma unroll
    for (int kk = 0; kk < 2; ++kk) {
      bf16x8 af[2], bfr[2];
#pragma unroll
      for (int mi = 0; mi < 2; ++mi) {
        int row = wr + mi * 16 + fr;
        int chunk = (kk * 4 + fq) ^ (row & 7);
        af[mi] = *(const bf16x8*)&As[row * 64 + chunk * 8];
      }
#pragma unroll
      for (int ni = 0; ni < 2; ++ni) {
        int row = wc + ni * 16 + fr;
        int chunk = (kk * 4 + fq) ^ (row & 7);
        bfr[ni] = *(const bf16x8*)&Bs[row * 64 + chunk * 8];
      }
#pragma unroll
      for (int mi = 0; mi < 2; ++mi)
#pragma unroll
        for (int ni = 0; ni < 2; ++ni)
          acc[mi][ni] =
              __builtin_amdgcn_mfma_f32_16x16x32_bf16(af[mi], bfr[ni], acc[mi][ni], 0, 0, 0);
    }
    __syncthreads();
  }

#pragma unroll
  for (int mi = 0; mi < 2; ++mi)
#pragma unroll
    for (int ni = 0; ni < 2; ++ni)
#pragma unroll
      for (int jj = 0; jj < 4; ++jj) {
        const int rr = tm * 64 + wr + mi * 16 + fq * 4 + jj;
        const int cc = n0 + wc + ni * 16 + fr;
        Ob[(long)rr * 4096 + cc] = acc[mi][ni][jj];
      }
}

extern "C" void kernel_launch(void* const* d_in, const int* in_sizes, int n_in,
                              void* d_out, int out_size, void* d_ws, size_t ws_size,
                              hipStream_t stream) {
  const float* x = (const float*)d_in[0];
  const float* xm = (const float*)d_in[1];
  const float* w = (const float*)d_in[2];
  float* out = (float*)d_out;

  const long B = 16, C = 256;

  float* simP = (float*)d_ws;                                // [4][B][C][C] fp32 (16.8 MB)
  unsigned short* Ps = (unsigned short*)(simP + 4 * B * C * C);  // [B][d][c] bf16 (2 MB)
  unsigned short* Ab = Ps + B * C * C;                       // [B][o][d] bf16 (2 MB)
  unsigned short* wb = Ab + B * C * C;                       // [o][c] bf16 (128 KB)

  // 1) w_conv -> bf16
  convert_bf16<<<dim3(32), dim3(256), 0, stream>>>(w, wb, C * C);
  // 2) simP = split-K(4) partials of scale * q q^T (x converted in-kernel)
  sim_split<<<dim3(1024), dim3(256), 0, stream>>>(x, simP);
  // 3) P = softmax(sum_q simP), stored transposed
  softmax4<<<dim3(1024), dim3(256), 0, stream>>>(simP, Ps);
  // 4) Ab = W * P + I   (residual folded into Ab)
  gemm_wp<<<dim3(16, 16), dim3(256), 0, stream>>>(wb, Ps, Ab);
  // 5) out = Ab * v     (v transposed+converted in-kernel from xm)
  gemm_out<<<dim3(4096), dim3(256), 0, stream>>>(Ab, xm, out);
}